// Round 9
// baseline (3136.999 us; speedup 1.0000x reference)
//
#include <hip/hip_runtime.h>

constexpr int kB   = 32;    // batch
constexpr int kNS  = 100;   // n_support
constexpr int kNW  = 10;    // n_way
constexpr int kNZ  = 1000;  // kNS*kNW
constexpr int kD   = 512;   // feature dim
constexpr int kNQ  = 150;   // N*Q query rows
constexpr int kIt  = 15;    // IPM iterations
constexpr int kPan = 8;     // pivots per panel (13 panels; was 4/25 — halves
                            //   the barrier+pivot-solve fixed cost per chain)
constexpr int kGrp = 8;     // row groups (one wave each) — 8x13 measured optimum
constexpr int kRQ  = 13;
constexpr int kNSP = kGrp * kRQ;   // 104 padded rows; rows 100..103 become
                                   // UNIT rows in the final panel (k0=96)

// -------------------------------------------------------------------------
// Fused gram+compat (unchanged, proven).
__global__ __launch_bounds__(256) void gemm_kernel(const float* __restrict__ sup,
                                                   const float* __restrict__ qry,
                                                   float* __restrict__ Kf,
                                                   float* __restrict__ compat)
{
    const int i0 = blockIdx.x * 2;
    const int b  = blockIdx.y;
    const int w    = threadIdx.x >> 6;
    const int lane = threadIdx.x & 63;
    const float* supb = sup + (size_t)b * kNS * kD;
    const float* qryb = qry + (size_t)b * kNQ * kD;
    const float4* r0 = reinterpret_cast<const float4*>(supb + (size_t)i0 * kD) + 2 * lane;
    const float4* r1 = reinterpret_cast<const float4*>(supb + (size_t)(i0 + 1) * kD) + 2 * lane;
    const float4 a0 = r0[0], a1 = r0[1];
    const float4 q0 = r1[0], q1 = r1[1];
    for (int t = w; t < kNS + kNQ; t += 4) {
        const float* rowt = (t < kNS) ? (supb + (size_t)t * kD)
                                      : (qryb + (size_t)(t - kNS) * kD);
        const float4* rt = reinterpret_cast<const float4*>(rowt) + 2 * lane;
        const float4 v0 = rt[0], v1 = rt[1];
        float pa = a0.x*v0.x + a0.y*v0.y + a0.z*v0.z + a0.w*v0.w
                 + a1.x*v1.x + a1.y*v1.y + a1.z*v1.z + a1.w*v1.w;
        float pb = q0.x*v0.x + q0.y*v0.y + q0.z*v0.z + q0.w*v0.w
                 + q1.x*v1.x + q1.y*v1.y + q1.z*v1.z + q1.w*v1.w;
        #pragma unroll
        for (int msk = 1; msk < 64; msk <<= 1) {
            pa += __shfl_xor(pa, msk);
            pb += __shfl_xor(pb, msk);
        }
        if (lane == 0) {
            if (t < kNS) {
                Kf[((size_t)b * kNS + i0    ) * kNS + t] = pa;
                Kf[((size_t)b * kNS + i0 + 1) * kNS + t] = pb;
            } else {
                compat[((size_t)b * kNS + i0    ) * kNQ + (t - kNS)] = pa;
                compat[((size_t)b * kNS + i0 + 1) * kNQ + (t - kNS)] = pb;
            }
        }
    }
}

// init also zeroes Sg (accumulated by ipm's epilogue atomics each iteration).
__global__ __launch_bounds__(256) void init_kernel(double* __restrict__ z,
                                                   double* __restrict__ nu,
                                                   double* __restrict__ s,
                                                   double* __restrict__ lam,
                                                   double* __restrict__ mu_g,
                                                   float* __restrict__ Sg)
{
    const int b = blockIdx.x;
    const int tid = threadIdx.x;
    for (int m = tid; m < kNZ; m += 256) {
        z[b*kNZ + m]   = 0.0;
        s[b*kNZ + m]   = 1.0;
        lam[b*kNZ + m] = 1.0;
    }
    for (int e = tid; e < kNS * kNS; e += 256) Sg[(size_t)b * kNS * kNS + e] = 0.0f;
    if (tid < kNS) nu[b*kNS + tid] = 0.0;
    if (tid == 0)  mu_g[b] = 1.0;   // dot(s0,lam0)/kNZ
}

// -------------------------------------------------------------------------
// fp32 4x4 adjugate full inverse.
__device__ __forceinline__ void adj4_invf(const float B[4][4], float I4[4][4])
{
    const float s0 = B[0][0]*B[1][1] - B[1][0]*B[0][1];
    const float s1 = B[0][0]*B[1][2] - B[1][0]*B[0][2];
    const float s2 = B[0][0]*B[1][3] - B[1][0]*B[0][3];
    const float s3 = B[0][1]*B[1][2] - B[1][1]*B[0][2];
    const float s4 = B[0][1]*B[1][3] - B[1][1]*B[0][3];
    const float s5 = B[0][2]*B[1][3] - B[1][2]*B[0][3];
    const float c5 = B[2][2]*B[3][3] - B[3][2]*B[2][3];
    const float c4 = B[2][1]*B[3][3] - B[3][1]*B[2][3];
    const float c3 = B[2][1]*B[3][2] - B[3][1]*B[2][2];
    const float c2 = B[2][0]*B[3][3] - B[3][0]*B[2][3];
    const float c1 = B[2][0]*B[3][2] - B[3][0]*B[2][2];
    const float c0 = B[2][0]*B[3][1] - B[3][0]*B[2][1];
    const float det = s0*c5 - s1*c4 + s2*c3 + s3*c2 - s4*c1 + s5*c0;
    const float id = 1.0f / det;
    I4[0][0] = ( B[1][1]*c5 - B[1][2]*c4 + B[1][3]*c3) * id;
    I4[0][1] = (-B[0][1]*c5 + B[0][2]*c4 - B[0][3]*c3) * id;
    I4[0][2] = ( B[3][1]*s5 - B[3][2]*s4 + B[3][3]*s3) * id;
    I4[0][3] = (-B[2][1]*s5 + B[2][2]*s4 - B[2][3]*s3) * id;
    I4[1][0] = (-B[1][0]*c5 + B[1][2]*c2 - B[1][3]*c1) * id;
    I4[1][1] = ( B[0][0]*c5 - B[0][2]*c2 + B[0][3]*c1) * id;
    I4[1][2] = (-B[3][0]*s5 + B[3][2]*s2 - B[3][3]*s1) * id;
    I4[1][3] = ( B[2][0]*s5 - B[2][2]*s2 + B[2][3]*s1) * id;
    I4[2][0] = ( B[1][0]*c4 - B[1][1]*c2 + B[1][3]*c0) * id;
    I4[2][1] = (-B[0][0]*c4 + B[0][1]*c2 - B[0][3]*c0) * id;
    I4[2][2] = ( B[3][0]*s4 - B[3][1]*s2 + B[3][3]*s0) * id;
    I4[2][3] = (-B[2][0]*s4 + B[2][1]*s2 - B[2][3]*s0) * id;
    I4[3][0] = (-B[1][0]*c3 + B[1][1]*c1 - B[1][2]*c0) * id;
    I4[3][1] = ( B[0][0]*c3 - B[0][1]*c1 + B[0][2]*c0) * id;
    I4[3][2] = (-B[3][0]*s3 + B[3][1]*s1 - B[3][2]*s0) * id;
    I4[3][3] = ( B[2][0]*s3 - B[2][1]*s1 + B[2][2]*s0) * id;
}

// fp32 4x4 adjugate solve: m1 = B^{-1} b1, m2 = B^{-1} b2.
__device__ __forceinline__ void adj4_solvef(const float B[4][4],
                                            const float b1[4], const float b2[4],
                                            float m1[4], float m2[4])
{
    const float s0 = B[0][0]*B[1][1] - B[1][0]*B[0][1];
    const float s1 = B[0][0]*B[1][2] - B[1][0]*B[0][2];
    const float s2 = B[0][0]*B[1][3] - B[1][0]*B[0][3];
    const float s3 = B[0][1]*B[1][2] - B[1][1]*B[0][2];
    const float s4 = B[0][1]*B[1][3] - B[1][1]*B[0][3];
    const float s5 = B[0][2]*B[1][3] - B[1][2]*B[0][3];
    const float c5 = B[2][2]*B[3][3] - B[3][2]*B[2][3];
    const float c4 = B[2][1]*B[3][3] - B[3][1]*B[2][3];
    const float c3 = B[2][1]*B[3][2] - B[3][1]*B[2][2];
    const float c2 = B[2][0]*B[3][3] - B[3][0]*B[2][3];
    const float c1 = B[2][0]*B[3][2] - B[3][0]*B[2][2];
    const float c0 = B[2][0]*B[3][1] - B[3][0]*B[2][1];
    const float det = s0*c5 - s1*c4 + s2*c3 + s3*c2 - s4*c1 + s5*c0;
    const float id = 1.0f / det;
    {
        const float r0 = ( B[1][1]*c5 - B[1][2]*c4 + B[1][3]*c3) * id;
        const float r1 = (-B[0][1]*c5 + B[0][2]*c4 - B[0][3]*c3) * id;
        const float r2 = ( B[3][1]*s5 - B[3][2]*s4 + B[3][3]*s3) * id;
        const float r3 = (-B[2][1]*s5 + B[2][2]*s4 - B[2][3]*s3) * id;
        m1[0] = r0*b1[0] + r1*b1[1] + r2*b1[2] + r3*b1[3];
        m2[0] = r0*b2[0] + r1*b2[1] + r2*b2[2] + r3*b2[3];
    }
    {
        const float r0 = (-B[1][0]*c5 + B[1][2]*c2 - B[1][3]*c1) * id;
        const float r1 = ( B[0][0]*c5 - B[0][2]*c2 + B[0][3]*c1) * id;
        const float r2 = (-B[3][0]*s5 + B[3][2]*s2 - B[3][3]*s1) * id;
        const float r3 = ( B[2][0]*s5 - B[2][2]*s2 + B[2][3]*s1) * id;
        m1[1] = r0*b1[0] + r1*b1[1] + r2*b1[2] + r3*b1[3];
        m2[1] = r0*b2[0] + r1*b2[1] + r2*b2[2] + r3*b2[3];
    }
    {
        const float r0 = ( B[1][0]*c4 - B[1][1]*c2 + B[1][3]*c0) * id;
        const float r1 = (-B[0][0]*c4 + B[0][1]*c2 - B[0][3]*c0) * id;
        const float r2 = ( B[3][0]*s4 - B[3][1]*s2 + B[3][3]*s0) * id;
        const float r3 = (-B[2][0]*s4 + B[2][1]*s2 - B[2][3]*s0) * id;
        m1[2] = r0*b1[0] + r1*b1[1] + r2*b1[2] + r3*b1[3];
        m2[2] = r0*b2[0] + r1*b2[1] + r2*b2[2] + r3*b2[3];
    }
    {
        const float r0 = (-B[1][0]*c3 + B[1][1]*c1 - B[1][2]*c0) * id;
        const float r1 = ( B[0][0]*c3 - B[0][1]*c1 + B[0][2]*c0) * id;
        const float r2 = (-B[3][0]*s3 + B[3][1]*s1 - B[3][2]*s0) * id;
        const float r3 = ( B[2][0]*s3 - B[2][1]*s1 + B[2][2]*s0) * id;
        m1[3] = r0*b1[0] + r1*b1[1] + r2*b1[2] + r3*b1[3];
        m2[3] = r0*b2[0] + r1*b2[1] + r2*b2[2] + r3*b2[3];
    }
}

// Rank-kPan update of the group's kRQ rows for TWO columns sharing each
// broadcast read.
#define PANEL_UPDATE2F(H1, H2, WSG, BUF, BASE, SCL1, SCL2, M1, M2)            \
    {                                                                          \
        _Pragma("unroll")                                                      \
        for (int r = 0; r < kRQ; ++r) { H1[r] *= SCL1; H2[r] *= SCL2; }        \
        _Pragma("unroll")                                                      \
        for (int p = 0; p < kPan; ++p) {                                       \
            const float mp1 = M1[p], mp2 = M2[p];                              \
            float w[kRQ];                                                      \
            _Pragma("unroll")                                                  \
            for (int u = 0; u < kRQ; ++u) w[u] = WSG[BUF][p][BASE + u];        \
            __builtin_amdgcn_sched_barrier(0);                                 \
            _Pragma("unroll")                                                  \
            for (int u = 0; u < kRQ; ++u) {                                    \
                H1[u] = fmaf(-mp1, w[u], H1[u]);                               \
                H2[u] = fmaf(-mp2, w[u], H2[u]);                               \
            }                                                                  \
        }                                                                      \
    }

// 8x8 pivot solve via Schur complement on 4x4 blocks. Register-staged to
// keep peak VGPR under the 128 cliff (2 blocks/CU). M = [[A,B],[C,D]]:
// y = A^{-1} bl; t = bh - C y; xh = (D - C A^{-1} B)^{-1} t; xl = y - A^{-1}B xh.
// Final panel (k0=96) has B=0, C=0, D=I (unit pad rows) -> degrades exactly.
#define PIVOT8_SOLVE(WR, BUF, K0, INP1, INP2, JC1, JC2, J1K, J2K, M1, M2)     \
    float M1[kPan], M2[kPan];                                                  \
    {                                                                          \
        float Ainv[4][4], AiB[4][4], y1[4], y2[4];                             \
        {                                                                      \
            float A4[4][4];                                                    \
            _Pragma("unroll")                                                  \
            for (int p = 0; p < 4; ++p)                                        \
                _Pragma("unroll")                                              \
                for (int q = 0; q < 4; ++q) A4[p][q] = WR[BUF][p][K0 + q];     \
            adj4_invf(A4, Ainv);                                               \
        }                                                                      \
        {                                                                      \
            float Bm[4][4];                                                    \
            _Pragma("unroll")                                                  \
            for (int p = 0; p < 4; ++p)                                        \
                _Pragma("unroll")                                              \
                for (int q = 0; q < 4; ++q) Bm[p][q] = WR[BUF][p][K0 + 4 + q]; \
            _Pragma("unroll")                                                  \
            for (int p = 0; p < 4; ++p)                                        \
                _Pragma("unroll")                                              \
                for (int q = 0; q < 4; ++q)                                    \
                    AiB[p][q] = Ainv[p][0]*Bm[0][q] + Ainv[p][1]*Bm[1][q]      \
                              + Ainv[p][2]*Bm[2][q] + Ainv[p][3]*Bm[3][q];     \
        }                                                                      \
        {                                                                      \
            float bl1[4], bl2[4];                                              \
            _Pragma("unroll")                                                  \
            for (int p = 0; p < 4; ++p) {                                      \
                bl1[p] = INP1 ? ((J1K == p) ? 1.0f : 0.0f) : WR[BUF][p][JC1];  \
                bl2[p] = INP2 ? ((J2K == p) ? 1.0f : 0.0f) : WR[BUF][p][JC2];  \
            }                                                                  \
            _Pragma("unroll")                                                  \
            for (int p = 0; p < 4; ++p) {                                      \
                y1[p] = Ainv[p][0]*bl1[0] + Ainv[p][1]*bl1[1]                  \
                      + Ainv[p][2]*bl1[2] + Ainv[p][3]*bl1[3];                 \
                y2[p] = Ainv[p][0]*bl2[0] + Ainv[p][1]*bl2[1]                  \
                      + Ainv[p][2]*bl2[2] + Ainv[p][3]*bl2[3];                 \
            }                                                                  \
        }                                                                      \
        {                                                                      \
            float Cm[4][4], S4[4][4], t1[4], t2[4];                            \
            _Pragma("unroll")                                                  \
            for (int p = 0; p < 4; ++p)                                        \
                _Pragma("unroll")                                              \
                for (int q = 0; q < 4; ++q) Cm[p][q] = WR[BUF][4 + p][K0 + q]; \
            _Pragma("unroll")                                                  \
            for (int p = 0; p < 4; ++p)                                        \
                _Pragma("unroll")                                              \
                for (int q = 0; q < 4; ++q)                                    \
                    S4[p][q] = WR[BUF][4 + p][K0 + 4 + q]                      \
                             - (Cm[p][0]*AiB[0][q] + Cm[p][1]*AiB[1][q]        \
                              + Cm[p][2]*AiB[2][q] + Cm[p][3]*AiB[3][q]);      \
            _Pragma("unroll")                                                  \
            for (int p = 0; p < 4; ++p) {                                      \
                const float bh1 = INP1 ? ((J1K == 4 + p) ? 1.0f : 0.0f)        \
                                       : WR[BUF][4 + p][JC1];                  \
                const float bh2 = INP2 ? ((J2K == 4 + p) ? 1.0f : 0.0f)        \
                                       : WR[BUF][4 + p][JC2];                  \
                t1[p] = bh1 - (Cm[p][0]*y1[0] + Cm[p][1]*y1[1]                 \
                             + Cm[p][2]*y1[2] + Cm[p][3]*y1[3]);               \
                t2[p] = bh2 - (Cm[p][0]*y2[0] + Cm[p][1]*y2[1]                 \
                             + Cm[p][2]*y2[2] + Cm[p][3]*y2[3]);               \
            }                                                                  \
            float xh1[4], xh2[4];                                              \
            adj4_solvef(S4, t1, t2, xh1, xh2);                                 \
            _Pragma("unroll")                                                  \
            for (int p = 0; p < 4; ++p) {                                      \
                M1[4 + p] = xh1[p];                                            \
                M2[4 + p] = xh2[p];                                            \
                M1[p] = y1[p] - (AiB[p][0]*xh1[0] + AiB[p][1]*xh1[1]           \
                               + AiB[p][2]*xh1[2] + AiB[p][3]*xh1[3]);         \
                M2[p] = y2[p] - (AiB[p][0]*xh2[0] + AiB[p][1]*xh2[1]           \
                               + AiB[p][2]*xh2[2] + AiB[p][3]*xh2[3]);         \
            }                                                                  \
        }                                                                      \
    }

// -------------------------------------------------------------------------
// One block (512 thr = 8 waves) per (b,a). Prologue applies the PREVIOUS
// iteration's state update inline; epilogue writes Hinv + atomic S-sum.
__global__ __launch_bounds__(512) void ipm_invert_kernel(
    const float* __restrict__ Kf, const int* __restrict__ labels,
    double* __restrict__ z, double* __restrict__ s, double* __restrict__ lam,
    const double* __restrict__ nu_in, double* __restrict__ nu_out,
    const double* __restrict__ dnu_g, const double* __restrict__ dz_g,
    const double* __restrict__ ds_g, const double* __restrict__ dl_g,
    const double* __restrict__ minr_g, const double* __restrict__ part3_g,
    double* __restrict__ mu_g,
    float* __restrict__ Hinv, float* __restrict__ Sg,
    double* __restrict__ tvec, const int first)
{
    const int b = blockIdx.x / kNW;
    const int a = blockIdx.x - b * kNW;
    const int tid = threadIdx.x;
    const int h = tid >> 6;            // row group 0..7
    const int lane = tid & 63;
    const int base = h * kRQ;
    const int j1 = lane;               // always < kNS
    const int j2 = 64 + lane;
    const bool a2 = (j2 < kNS);        // lane < 36
    const int js2 = a2 ? j2 : j1;

    __shared__ double za[kNS], sa[kNS], la[kNS], nus[kNS], r1s[kNS];
    __shared__ float  daf[kNS];
    __shared__ double part[kGrp][kNS];
    __shared__ alignas(16) float Wr [2][kPan][kNSP + 8];
    __shared__ alignas(16) float Wsg[2][kPan][kNSP + 8];
    __shared__ int labs[kNS];

    const float* Kb = Kf + (size_t)b * kNS * kNS;

    double mu = 1.0;
    if (tid < kNS) {
        double alpha = 0.0;
        if (!first) {
            double am = 1e300;
            #pragma unroll
            for (int aa = 0; aa < kNW; ++aa) am = fmin(am, minr_g[b * kNW + aa]);
            alpha = fmin(1.0, 0.99 * am);
            double P0 = 0.0, P1 = 0.0, P2 = 0.0;
            #pragma unroll
            for (int aa = 0; aa < kNW; ++aa) {
                const double* pp = part3_g + (size_t)(b * kNW + aa) * 3;
                P0 += pp[0]; P1 += pp[1]; P2 += pp[2];
            }
            mu = (P0 + alpha * (P1 + alpha * P2)) / kNZ;
        }
        const size_t m = (size_t)b * kNZ + tid * kNW + a;
        double zv = z[m], sv = s[m], lv = lam[m];
        double nv = nu_in[b * kNS + tid];
        if (!first) {
            zv += alpha * dz_g[m]; sv += alpha * ds_g[m]; lv += alpha * dl_g[m];
            z[m] = zv; s[m] = sv; lam[m] = lv;          // own slice: race-free
            nv += alpha * dnu_g[b * kNS + tid];
        }
        if (a == 0) {
            nu_out[b * kNS + tid] = nv;                 // parity buffer
            if (tid == 0) mu_g[b] = mu;                 // relay for dz
        }
        za[tid] = zv; sa[tid] = sv; la[tid] = lv;
        daf[tid] = (float)(lv / sv);
        nus[tid] = nv;
        labs[tid] = labels[b * kNS + tid];
    }
    // pad COLUMN slots (100..103) stay exact zero in both buffers
    if (h == 0 && j2 >= kNS && j2 < kNSP) {
        #pragma unroll
        for (int bf = 0; bf < 2; ++bf)
            #pragma unroll
            for (int p = 0; p < kPan; ++p) { Wr[bf][p][j2] = 0.0f; Wsg[bf][p][j2] = 0.0f; }
    }
    __syncthreads();

    // Build both H columns (fp32); fused fp64 partials of (K z_a).
    float h1[kRQ], h2[kRQ];
    double kz1 = 0.0, kz2 = 0.0;
    #pragma unroll
    for (int r = 0; r < kRQ; ++r) {
        const int i = base + r;
        if (i < kNS) {
            float kv1 = Kb[(size_t)i * kNS + j1];
            float kv2 = Kb[(size_t)i * kNS + js2];
            kz1 += (double)kv1 * za[i];
            kz2 += (double)kv2 * za[i];
            h1[r] = (i == j1)  ? (kv1 + 1.0f + daf[j1])  : kv1;
            h2[r] = (i == js2) ? (kv2 + 1.0f + daf[js2]) : kv2;
        } else { h1[r] = 0.0f; h2[r] = 0.0f; }
    }
    part[h][j1] = kz1;
    if (a2) part[h][j2] = kz2;
    if (h == 0) {   // seed panel 0 rows (0..7); sign vs k0=0 -> all +
        #pragma unroll
        for (int p = 0; p < kPan; ++p) {
            Wr [0][p][j1] = h1[p];  Wsg[0][p][j1] = h1[p];
            if (a2) { Wr[0][p][j2] = h2[p]; Wsg[0][p][j2] = h2[p]; }
        }
    }
    __syncthreads();
    if (tid < kNS) {
        const int i = tid;
        double kz = 0.0;
        #pragma unroll
        for (int g = 0; g < kGrp; ++g) kz += part[g][i];
        double yv = (labs[i] == a) ? 1.0 : 0.0;
        double rd = kz + za[i] - yv + la[i] + nus[i];
        double rp = za[i] + sa[i] - 0.1 * yv;      // h = C_REG*y
        double rc = la[i] * sa[i] - 0.1 * mu;      // sigma = 0.1
        r1s[i] = -rd + (rc - la[i] * rp) / sa[i];
    }

    // Panel-blocked Gauss-Jordan inverse: 13 panels, 1 barrier each.
    #pragma unroll 1
    for (int k0 = 0; k0 < kNS; k0 += kPan) {
        const int buf = (k0 / kPan) & 1, nbuf = 1 - buf;
        __syncthreads();                     // Wr/Wsg[buf] complete

        const bool inp1 = (j1 >= k0) && (j1 < k0 + kPan);
        const bool inp2 = (js2 >= k0) && (js2 < k0 + kPan);
        const int  j1k  = j1  - k0;
        const int  j2k  = js2 - k0;
        PIVOT8_SOLVE(Wr, buf, k0, inp1, inp2, j1, js2, j1k, j2k, m1, m2);
        const float scl1 = inp1 ? 0.0f : 1.0f;
        const float scl2 = inp2 ? 0.0f : 1.0f;
        PANEL_UPDATE2F(h1, h2, Wsg, buf, base, scl1, scl2, m1, m2);

        // panel rows get m directly (overwrite generic update)
        if (k0 < base + kRQ && k0 + kPan - 1 >= base) {
            #pragma unroll
            for (int r = 0; r < kRQ; ++r) {
                const int i = base + r;
                if (i >= k0 && i < k0 + kPan) {
                    const int p = i - k0;
                    h1[r] = m1[p];
                    h2[r] = m2[p];
                }
            }
        }
        // write-ahead next panel rows (raw + signed vs kn0)
        const int kn0 = k0 + kPan;
        if (kn0 < kNS && kn0 < base + kRQ && kn0 + kPan - 1 >= base) {
            #pragma unroll
            for (int r = 0; r < kRQ; ++r) {
                const int i = base + r;
                if (i >= kn0 && i < kn0 + kPan) {
                    const int p = i - kn0;
                    Wr [nbuf][p][j1] = h1[r];
                    Wsg[nbuf][p][j1] = (j1 < kn0) ? -h1[r] : h1[r];
                    if (a2) {
                        Wr [nbuf][p][j2] = h2[r];
                        Wsg[nbuf][p][j2] = (j2 < kn0) ? -h2[r] : h2[r];
                    }
                }
            }
        }
        // final panel (96..103): pad rows 100..103 become UNIT rows so the
        // 8x8 pivot block is [[A,0],[0,I]] (nonsingular, exact no-op).
        if (kn0 == 96 && tid < 4) {
            Wr [nbuf][4 + tid][100 + tid] = 1.0f;
            Wsg[nbuf][4 + tid][100 + tid] = 1.0f;
        }
    }

    // Write Hinv (fp32, coalesced) + atomic S accumulation + t_a = Hinv*r1.
    float* Hb = Hinv + (size_t)(b * kNW + a) * kNS * kNS;
    float* Sb = Sg   + (size_t)b * kNS * kNS;
    double tp1 = 0.0, tp2 = 0.0;
    #pragma unroll
    for (int r = 0; r < kRQ; ++r) {
        const int i = base + r;
        if (i < kNS) {
            Hb[(size_t)i * kNS + j1] = h1[r];
            atomicAdd(&Sb[(size_t)i * kNS + j1], h1[r]);
            tp1 += (double)h1[r] * r1s[i];
            if (a2) {
                Hb[(size_t)i * kNS + j2] = h2[r];
                atomicAdd(&Sb[(size_t)i * kNS + j2], h2[r]);
                tp2 += (double)h2[r] * r1s[i];
            }
        }
    }
    part[h][j1] = tp1;
    if (a2) part[h][j2] = tp2;
    __syncthreads();
    if (tid < kNS) {
        double t = 0.0;
        #pragma unroll
        for (int g = 0; g < kGrp; ++g) t += part[g][tid];
        tvec[(size_t)(b * kNW + a) * kNS + tid] = t;
    }
}

// -------------------------------------------------------------------------
// One block (512 thr) per b: fp32 panel-blocked GJ solve S dnu = sum_a t_a + rp2.
// RHS column stored at slot kNSP (=104) so it can NEVER enter a pivot block.
__global__ __launch_bounds__(512) void schur_solve_kernel(
    const float* __restrict__ Sg, const double* __restrict__ tvec,
    const double* __restrict__ z, double* __restrict__ dnu_g)
{
    const int b = blockIdx.x;
    const int tid = threadIdx.x;
    const int h = tid >> 6;
    const int lane = tid & 63;
    const int base = h * kRQ;
    const int j1 = lane;
    const int j2 = 64 + lane;
    const bool a2 = (j2 <= kNS);       // lane <= 36; j2==100 is the rhs column
    const bool isrhs = (j2 == kNS);
    const int js2 = a2 ? j2 : j1;      // logical column
    const int jc2 = isrhs ? kNSP : js2; // STORAGE column (rhs -> 104)

    __shared__ double rhs[kNS];
    __shared__ alignas(16) float Wr [2][kPan][kNSP + 8];
    __shared__ alignas(16) float Wsg[2][kPan][kNSP + 8];

    const float*  Sb = Sg   + (size_t)b * kNS * kNS;
    const double* tb = tvec + (size_t)b * kNW * kNS;
    const double* zb = z    + (size_t)b * kNZ;

    if (tid < kNS) {
        double acc = 0.0, rp2 = 0.0;
        #pragma unroll
        for (int a = 0; a < kNW; ++a) {
            acc += tb[a * kNS + tid];
            rp2 += zb[tid * kNW + a];
        }
        rhs[tid] = acc + rp2;
    }
    if (h == 0 && j2 >= kNS && j2 < kNSP) {   // pad cols 100..103 -> zero
        #pragma unroll
        for (int bf = 0; bf < 2; ++bf)
            #pragma unroll
            for (int p = 0; p < kPan; ++p) { Wr[bf][p][j2] = 0.0f; Wsg[bf][p][j2] = 0.0f; }
    }
    __syncthreads();

    float h1[kRQ], h2[kRQ];
    #pragma unroll
    for (int r = 0; r < kRQ; ++r) {
        const int i = base + r;
        if (i < kNS) {
            h1[r] = Sb[(size_t)i * kNS + j1];
            h2[r] = isrhs ? (float)rhs[i]
                  : Sb[(size_t)i * kNS + ((js2 < kNS) ? js2 : 0)];
        } else { h1[r] = 0.0f; h2[r] = 0.0f; }
    }
    if (h == 0) {
        #pragma unroll
        for (int p = 0; p < kPan; ++p) {
            Wr [0][p][j1] = h1[p];  Wsg[0][p][j1] = h1[p];
            if (a2) { Wr[0][p][jc2] = h2[p]; Wsg[0][p][jc2] = h2[p]; }
        }
    }

    #pragma unroll 1
    for (int k0 = 0; k0 < kNS; k0 += kPan) {
        const int buf = (k0 / kPan) & 1, nbuf = 1 - buf;
        __syncthreads();

        const bool inp1 = (j1 >= k0) && (j1 < k0 + kPan);
        const bool inp2 = !isrhs && (js2 >= k0) && (js2 < k0 + kPan);
        const int  j1k  = j1  - k0;
        const int  j2k  = js2 - k0;
        PIVOT8_SOLVE(Wr, buf, k0, inp1, inp2, j1, jc2, j1k, j2k, m1, m2);
        const float scl1 = inp1 ? 0.0f : 1.0f;
        const float scl2 = inp2 ? 0.0f : 1.0f;
        PANEL_UPDATE2F(h1, h2, Wsg, buf, base, scl1, scl2, m1, m2);

        if (k0 < base + kRQ && k0 + kPan - 1 >= base) {
            #pragma unroll
            for (int r = 0; r < kRQ; ++r) {
                const int i = base + r;
                if (i >= k0 && i < k0 + kPan) {
                    const int p = i - k0;
                    h1[r] = m1[p];
                    h2[r] = m2[p];
                }
            }
        }
        const int kn0 = k0 + kPan;
        if (kn0 < kNS && kn0 < base + kRQ && kn0 + kPan - 1 >= base) {
            #pragma unroll
            for (int r = 0; r < kRQ; ++r) {
                const int i = base + r;
                if (i >= kn0 && i < kn0 + kPan) {
                    const int p = i - kn0;
                    Wr [nbuf][p][j1] = h1[r];
                    Wsg[nbuf][p][j1] = (j1 < kn0) ? -h1[r] : h1[r];
                    if (a2) {
                        Wr [nbuf][p][jc2] = h2[r];
                        Wsg[nbuf][p][jc2] = (j2 < kn0) ? -h2[r] : h2[r];
                    }
                }
            }
        }
        if (kn0 == 96 && tid < 4) {   // unit pad rows for the final panel
            Wr [nbuf][4 + tid][100 + tid] = 1.0f;
            Wsg[nbuf][4 + tid][100 + tid] = 1.0f;
        }
    }

    if (isrhs) {   // lane 36: rhs column now holds dnu for owned rows
        #pragma unroll
        for (int r = 0; r < kRQ; ++r) {
            const int i = base + r;
            if (i < kNS) dnu_g[(size_t)b * kNS + i] = (double)h2[r];
        }
    }
}

// -------------------------------------------------------------------------
// One block (512 thr) per (b,a): dz_a = t_a - Hinv_a*dnu, ds/dlam, per-block
// min step-ratio, 3 quadratic mu-partials, zero Sg for next iteration.
__global__ __launch_bounds__(512) void dz_kernel(
    const int* __restrict__ labels,
    const float* __restrict__ Hinv, const double* __restrict__ tvec,
    const double* __restrict__ dnu_g,
    const double* __restrict__ z, const double* __restrict__ s,
    const double* __restrict__ lam, const double* __restrict__ mu_g,
    double* __restrict__ dz_g, double* __restrict__ ds_g,
    double* __restrict__ dl_g, double* __restrict__ minr_g,
    double* __restrict__ part3_g, float* __restrict__ Sg)
{
    const int b = blockIdx.x / kNW;
    const int a = blockIdx.x - b * kNW;
    const int tid = threadIdx.x;
    const int h = tid >> 7;            // 0..3
    const int j = tid & 127;

    __shared__ double dnus[kNS];
    __shared__ double p4[4][kNS];
    __shared__ double red[512], rA[512], rB[512], rC[512];

    const float* Hb = Hinv + (size_t)(b * kNW + a) * kNS * kNS;

    if (tid < kNS) dnus[tid] = dnu_g[(size_t)b * kNS + tid];
    {
        float* Sb = Sg + (size_t)b * kNS * kNS + (size_t)a * (kNS * kNS / kNW);
        for (int e = tid; e < kNS * kNS / kNW; e += 512) Sb[e] = 0.0f;
    }
    __syncthreads();

    if (j < kNS) {
        double p = 0.0;
        #pragma unroll
        for (int r = 0; r < kNS / 4; ++r)
            p += (double)Hb[(size_t)(h * (kNS / 4) + r) * kNS + j] * dnus[h * (kNS / 4) + r];
        p4[h][j] = p;
    }
    __syncthreads();

    double lmin = 1e300, p0 = 0.0, p1 = 0.0, p2 = 0.0;
    if (tid < kNS) {
        const int i = tid;
        const size_t m = (size_t)b * kNZ + i * kNW + a;
        const double mu = mu_g[b];
        double dz = tvec[(size_t)(b * kNW + a) * kNS + i]
                  - (p4[0][i] + p4[1][i] + p4[2][i] + p4[3][i]);
        double yv = (labels[b * kNS + i] == a) ? 1.0 : 0.0;
        double zv = z[m], sv = s[m], lv = lam[m];
        double rp = zv + sv - 0.1 * yv;
        double rc = lv * sv - 0.1 * mu;
        double ds = -rp - dz;
        double dl = (-rc - lv * ds) / sv;
        dz_g[m] = dz; ds_g[m] = ds; dl_g[m] = dl;
        if (ds < 0.0) lmin = fmin(lmin, -sv / ds);
        if (dl < 0.0) lmin = fmin(lmin, -lv / dl);
        p0 = sv * lv;
        p1 = sv * dl + lv * ds;
        p2 = ds * dl;
    }
    red[tid] = lmin; rA[tid] = p0; rB[tid] = p1; rC[tid] = p2;
    __syncthreads();
    for (int off = 256; off > 0; off >>= 1) {
        if (tid < off) {
            red[tid] = fmin(red[tid], red[tid + off]);
            rA[tid] += rA[tid + off];
            rB[tid] += rB[tid + off];
            rC[tid] += rC[tid + off];
        }
        __syncthreads();
    }
    if (tid == 0) {
        minr_g[b * kNW + a] = red[0];
        double* pp = part3_g + (size_t)(b * kNW + a) * 3;
        pp[0] = rA[0]; pp[1] = rB[0]; pp[2] = rC[0];
    }
}

// -------------------------------------------------------------------------
// logits: widened to 320 blocks (10 q-chunks of 15 per b; was 32 blocks).
// z_final applies the 15th (final) IPM step inline.
__global__ __launch_bounds__(256) void logits_kernel(const float* __restrict__ compat,
                                                     const double* __restrict__ z,
                                                     const double* __restrict__ dz_g,
                                                     const double* __restrict__ minr_g,
                                                     float* __restrict__ out)
{
    const int b = blockIdx.x / kNW;
    const int c = blockIdx.x - b * kNW;   // q-chunk 0..9
    const int tid = threadIdx.x;
    const float* cb = compat + (size_t)b * kNS * kNQ;
    const double* zb = z + (size_t)b * kNZ;
    __shared__ double zs[kNZ];
    double am = 1e300;
    #pragma unroll
    for (int aa = 0; aa < kNW; ++aa) am = fmin(am, minr_g[b * kNW + aa]);
    const double alpha = fmin(1.0, 0.99 * am);
    for (int m = tid; m < kNZ; m += 256)
        zs[m] = zb[m] + alpha * dz_g[(size_t)b * kNZ + m];
    __syncthreads();
    for (int idx = tid; idx < (kNQ / kNW) * kNW; idx += 256) {  // 150 items
        int ql = idx / kNW, n = idx - ql * kNW;
        int q = c * (kNQ / kNW) + ql;
        double acc = 0.0;
        for (int s2 = 0; s2 < kNS; ++s2)
            acc += (double)cb[(size_t)s2 * kNQ + q] * zs[s2 * kNW + n];
        out[(size_t)b * kNQ * kNW + q * kNW + n] = (float)acc;
    }
}

// -------------------------------------------------------------------------
extern "C" void kernel_launch(void* const* d_in, const int* in_sizes, int n_in,
                              void* d_out, int out_size, void* d_ws, size_t ws_size,
                              hipStream_t stream)
{
    const float* sup    = (const float*)d_in[0];   // (32,10,10,512)
    const int*   labels = (const int*)  d_in[1];   // (32,10,10)
    const float* qry    = (const float*)d_in[2];   // (32,10,15,512)
    float* out = (float*)d_out;                    // (32,150,10) fp32

    char* ws = (char*)d_ws;
    size_t off = 0;
    auto alloc = [&](size_t bytes) -> void* {
        void* p = ws + off;
        off += (bytes + 255) & ~(size_t)255;
        return p;
    };
    float*  Kf     = (float*) alloc(sizeof(float)  * kB * kNS * kNS);        // 1.28 MB
    double* z      = (double*)alloc(sizeof(double) * kB * kNZ);
    double* nuA    = (double*)alloc(sizeof(double) * kB * kNS);
    double* nuB    = (double*)alloc(sizeof(double) * kB * kNS);
    double* s      = (double*)alloc(sizeof(double) * kB * kNZ);
    double* lam    = (double*)alloc(sizeof(double) * kB * kNZ);
    double* mu_g   = (double*)alloc(sizeof(double) * kB);
    float*  Hinv   = (float*) alloc(sizeof(float)  * kB * kNW * kNS * kNS);  // 12.8 MB
    float*  Sg     = (float*) alloc(sizeof(float)  * kB * kNS * kNS);        // 1.28 MB
    double* tvec   = (double*)alloc(sizeof(double) * kB * kNW * kNS);
    double* dnu_g  = (double*)alloc(sizeof(double) * kB * kNS);
    double* dz_g   = (double*)alloc(sizeof(double) * kB * kNZ);
    double* ds_g   = (double*)alloc(sizeof(double) * kB * kNZ);
    double* dl_g   = (double*)alloc(sizeof(double) * kB * kNZ);
    double* minr_g = (double*)alloc(sizeof(double) * kB * kNW);
    double* part3_g= (double*)alloc(sizeof(double) * kB * kNW * 3);
    float*  compat = (float*) alloc(sizeof(float)  * kB * kNS * kNQ);        // 1.92 MB

    gemm_kernel<<<dim3(kNS / 2, kB), 256, 0, stream>>>(sup, qry, Kf, compat);
    init_kernel<<<kB, 256, 0, stream>>>(z, nuA, s, lam, mu_g, Sg);

    for (int it = 0; it < kIt; ++it) {
        const double* nu_in  = (it & 1) ? nuB : nuA;
        double*       nu_out = (it & 1) ? nuA : nuB;
        ipm_invert_kernel<<<kB * kNW, 512, 0, stream>>>(
            Kf, labels, z, s, lam, nu_in, nu_out,
            dnu_g, dz_g, ds_g, dl_g, minr_g, part3_g, mu_g,
            Hinv, Sg, tvec, (it == 0) ? 1 : 0);
        schur_solve_kernel<<<kB, 512, 0, stream>>>(Sg, tvec, z, dnu_g);
        dz_kernel<<<kB * kNW, 512, 0, stream>>>(labels, Hinv, tvec, dnu_g,
                                                z, s, lam, mu_g,
                                                dz_g, ds_g, dl_g, minr_g,
                                                part3_g, Sg);
    }

    logits_kernel<<<kB * kNW, 256, 0, stream>>>(compat, z, dz_g, minr_g, out);
}

// Round 10
// 2399.392 us; speedup vs baseline: 1.3074x; 1.3074x over previous
//
#include <hip/hip_runtime.h>

constexpr int kB   = 32;    // batch
constexpr int kNS  = 100;   // n_support
constexpr int kNW  = 10;    // n_way
constexpr int kNZ  = 1000;  // kNS*kNW
constexpr int kD   = 512;   // feature dim
constexpr int kNQ  = 150;   // N*Q query rows
constexpr int kIt  = 15;    // IPM iterations
constexpr int kPan = 4;     // pivots per panel — MEASURED OPTIMUM (8 regressed:
                            //   VGPR 92/LDS 25.6KB cut occupancy, 8x8 pivot
                            //   solve lengthened the serial chain; r9 144us)
constexpr int kGrp = 8;     // row groups — 8x13 measured optimum (4x25, 16x7 slower)
constexpr int kRQ  = 13;
constexpr int kNSP = kGrp * kRQ;   // 104 padded rows (pads are exact zeros)

// -------------------------------------------------------------------------
// Fused gram+compat (proven).
__global__ __launch_bounds__(256) void gemm_kernel(const float* __restrict__ sup,
                                                   const float* __restrict__ qry,
                                                   float* __restrict__ Kf,
                                                   float* __restrict__ compat)
{
    const int i0 = blockIdx.x * 2;
    const int b  = blockIdx.y;
    const int w    = threadIdx.x >> 6;
    const int lane = threadIdx.x & 63;
    const float* supb = sup + (size_t)b * kNS * kD;
    const float* qryb = qry + (size_t)b * kNQ * kD;
    const float4* r0 = reinterpret_cast<const float4*>(supb + (size_t)i0 * kD) + 2 * lane;
    const float4* r1 = reinterpret_cast<const float4*>(supb + (size_t)(i0 + 1) * kD) + 2 * lane;
    const float4 a0 = r0[0], a1 = r0[1];
    const float4 q0 = r1[0], q1 = r1[1];
    for (int t = w; t < kNS + kNQ; t += 4) {
        const float* rowt = (t < kNS) ? (supb + (size_t)t * kD)
                                      : (qryb + (size_t)(t - kNS) * kD);
        const float4* rt = reinterpret_cast<const float4*>(rowt) + 2 * lane;
        const float4 v0 = rt[0], v1 = rt[1];
        float pa = a0.x*v0.x + a0.y*v0.y + a0.z*v0.z + a0.w*v0.w
                 + a1.x*v1.x + a1.y*v1.y + a1.z*v1.z + a1.w*v1.w;
        float pb = q0.x*v0.x + q0.y*v0.y + q0.z*v0.z + q0.w*v0.w
                 + q1.x*v1.x + q1.y*v1.y + q1.z*v1.z + q1.w*v1.w;
        #pragma unroll
        for (int msk = 1; msk < 64; msk <<= 1) {
            pa += __shfl_xor(pa, msk);
            pb += __shfl_xor(pb, msk);
        }
        if (lane == 0) {
            if (t < kNS) {
                Kf[((size_t)b * kNS + i0    ) * kNS + t] = pa;
                Kf[((size_t)b * kNS + i0 + 1) * kNS + t] = pb;
            } else {
                compat[((size_t)b * kNS + i0    ) * kNQ + (t - kNS)] = pa;
                compat[((size_t)b * kNS + i0 + 1) * kNQ + (t - kNS)] = pb;
            }
        }
    }
}

// init also zeroes Sg (accumulated by ipm's epilogue atomics each iteration).
__global__ __launch_bounds__(256) void init_kernel(double* __restrict__ z,
                                                   double* __restrict__ nu,
                                                   double* __restrict__ s,
                                                   double* __restrict__ lam,
                                                   double* __restrict__ mu_g,
                                                   float* __restrict__ Sg)
{
    const int b = blockIdx.x;
    const int tid = threadIdx.x;
    for (int m = tid; m < kNZ; m += 256) {
        z[b*kNZ + m]   = 0.0;
        s[b*kNZ + m]   = 1.0;
        lam[b*kNZ + m] = 1.0;
    }
    for (int e = tid; e < kNS * kNS; e += 256) Sg[(size_t)b * kNS * kNS + e] = 0.0f;
    if (tid < kNS) nu[b*kNS + tid] = 0.0;
    if (tid == 0)  mu_g[b] = 1.0;   // dot(s0,lam0)/kNZ
}

// -------------------------------------------------------------------------
// fp32 4x4 adjugate solve: m1 = B^{-1} b1, m2 = B^{-1} b2.
__device__ __forceinline__ void adj4_solvef(const float B[4][4],
                                            const float b1[4], const float b2[4],
                                            float m1[4], float m2[4])
{
    const float s0 = B[0][0]*B[1][1] - B[1][0]*B[0][1];
    const float s1 = B[0][0]*B[1][2] - B[1][0]*B[0][2];
    const float s2 = B[0][0]*B[1][3] - B[1][0]*B[0][3];
    const float s3 = B[0][1]*B[1][2] - B[1][1]*B[0][2];
    const float s4 = B[0][1]*B[1][3] - B[1][1]*B[0][3];
    const float s5 = B[0][2]*B[1][3] - B[1][2]*B[0][3];
    const float c5 = B[2][2]*B[3][3] - B[3][2]*B[2][3];
    const float c4 = B[2][1]*B[3][3] - B[3][1]*B[2][3];
    const float c3 = B[2][1]*B[3][2] - B[3][1]*B[2][2];
    const float c2 = B[2][0]*B[3][3] - B[3][0]*B[2][3];
    const float c1 = B[2][0]*B[3][2] - B[3][0]*B[2][2];
    const float c0 = B[2][0]*B[3][1] - B[3][0]*B[2][1];
    const float det = s0*c5 - s1*c4 + s2*c3 + s3*c2 - s4*c1 + s5*c0;
    const float id = 1.0f / det;
    {
        const float r0 = ( B[1][1]*c5 - B[1][2]*c4 + B[1][3]*c3) * id;
        const float r1 = (-B[0][1]*c5 + B[0][2]*c4 - B[0][3]*c3) * id;
        const float r2 = ( B[3][1]*s5 - B[3][2]*s4 + B[3][3]*s3) * id;
        const float r3 = (-B[2][1]*s5 + B[2][2]*s4 - B[2][3]*s3) * id;
        m1[0] = r0*b1[0] + r1*b1[1] + r2*b1[2] + r3*b1[3];
        m2[0] = r0*b2[0] + r1*b2[1] + r2*b2[2] + r3*b2[3];
    }
    {
        const float r0 = (-B[1][0]*c5 + B[1][2]*c2 - B[1][3]*c1) * id;
        const float r1 = ( B[0][0]*c5 - B[0][2]*c2 + B[0][3]*c1) * id;
        const float r2 = (-B[3][0]*s5 + B[3][2]*s2 - B[3][3]*s1) * id;
        const float r3 = ( B[2][0]*s5 - B[2][2]*s2 + B[2][3]*s1) * id;
        m1[1] = r0*b1[0] + r1*b1[1] + r2*b1[2] + r3*b1[3];
        m2[1] = r0*b2[0] + r1*b2[1] + r2*b2[2] + r3*b2[3];
    }
    {
        const float r0 = ( B[1][0]*c4 - B[1][1]*c2 + B[1][3]*c0) * id;
        const float r1 = (-B[0][0]*c4 + B[0][1]*c2 - B[0][3]*c0) * id;
        const float r2 = ( B[3][0]*s4 - B[3][1]*s2 + B[3][3]*s0) * id;
        const float r3 = (-B[2][0]*s4 + B[2][1]*s2 - B[2][3]*s0) * id;
        m1[2] = r0*b1[0] + r1*b1[1] + r2*b1[2] + r3*b1[3];
        m2[2] = r0*b2[0] + r1*b2[1] + r2*b2[2] + r3*b2[3];
    }
    {
        const float r0 = (-B[1][0]*c3 + B[1][1]*c1 - B[1][2]*c0) * id;
        const float r1 = ( B[0][0]*c3 - B[0][1]*c1 + B[0][2]*c0) * id;
        const float r2 = (-B[3][0]*s3 + B[3][1]*s1 - B[3][2]*s0) * id;
        const float r3 = ( B[2][0]*s3 - B[2][1]*s1 + B[2][2]*s0) * id;
        m1[3] = r0*b1[0] + r1*b1[1] + r2*b1[2] + r3*b1[3];
        m2[3] = r0*b2[0] + r1*b2[1] + r2*b2[2] + r3*b2[3];
    }
}

// Rank-4 update of the group's kRQ rows for TWO columns sharing each
// broadcast read. fp32 (2x VALU rate, half the LDS bytes vs fp64).
#define PANEL_UPDATE2F(H1, H2, WSG, BUF, BASE, SCL1, SCL2, M1, M2)            \
    {                                                                          \
        _Pragma("unroll")                                                      \
        for (int r = 0; r < kRQ; ++r) { H1[r] *= SCL1; H2[r] *= SCL2; }        \
        _Pragma("unroll")                                                      \
        for (int p = 0; p < kPan; ++p) {                                       \
            const float mp1 = M1[p], mp2 = M2[p];                              \
            float w[kRQ];                                                      \
            _Pragma("unroll")                                                  \
            for (int u = 0; u < kRQ; ++u) w[u] = WSG[BUF][p][BASE + u];        \
            __builtin_amdgcn_sched_barrier(0);                                 \
            _Pragma("unroll")                                                  \
            for (int u = 0; u < kRQ; ++u) {                                    \
                H1[u] = fmaf(-mp1, w[u], H1[u]);                               \
                H2[u] = fmaf(-mp2, w[u], H2[u]);                               \
            }                                                                  \
        }                                                                      \
    }

// -------------------------------------------------------------------------
// One block (512 thr = 8 waves) per (b,a). Prologue applies the PREVIOUS
// iteration's state update inline (replaces update_kernel). Epilogue writes
// Hinv AND atomically accumulates S = sum_a Hinv_a (replaces sbuild_kernel).
__global__ __launch_bounds__(512) void ipm_invert_kernel(
    const float* __restrict__ Kf, const int* __restrict__ labels,
    double* __restrict__ z, double* __restrict__ s, double* __restrict__ lam,
    const double* __restrict__ nu_in, double* __restrict__ nu_out,
    const double* __restrict__ dnu_g, const double* __restrict__ dz_g,
    const double* __restrict__ ds_g, const double* __restrict__ dl_g,
    const double* __restrict__ minr_g, const double* __restrict__ part3_g,
    double* __restrict__ mu_g,
    float* __restrict__ Hinv, float* __restrict__ Sg,
    double* __restrict__ tvec, const int first)
{
    const int b = blockIdx.x / kNW;
    const int a = blockIdx.x - b * kNW;
    const int tid = threadIdx.x;
    const int h = tid >> 6;            // row group 0..7
    const int lane = tid & 63;
    const int base = h * kRQ;
    const int j1 = lane;               // always < kNS
    const int j2 = 64 + lane;
    const bool a2 = (j2 < kNS);        // lane < 36
    const int js2 = a2 ? j2 : j1;

    __shared__ double za[kNS], sa[kNS], la[kNS], nus[kNS], r1s[kNS];
    __shared__ float  daf[kNS];
    __shared__ double part[kGrp][kNS];
    __shared__ alignas(16) float Wr [2][kPan][kNSP + 8];  // raw panel rows
    __shared__ alignas(16) float Wsg[2][kPan][kNSP + 8];  // signed panel rows
    __shared__ int labs[kNS];

    const float* Kb = Kf + (size_t)b * kNS * kNS;

    double mu = 1.0;
    if (tid < kNS) {
        double alpha = 0.0;
        if (!first) {
            double am = 1e300;
            #pragma unroll
            for (int aa = 0; aa < kNW; ++aa) am = fmin(am, minr_g[b * kNW + aa]);
            alpha = fmin(1.0, 0.99 * am);
            double P0 = 0.0, P1 = 0.0, P2 = 0.0;
            #pragma unroll
            for (int aa = 0; aa < kNW; ++aa) {
                const double* pp = part3_g + (size_t)(b * kNW + aa) * 3;
                P0 += pp[0]; P1 += pp[1]; P2 += pp[2];
            }
            mu = (P0 + alpha * (P1 + alpha * P2)) / kNZ;
        }
        const size_t m = (size_t)b * kNZ + tid * kNW + a;
        double zv = z[m], sv = s[m], lv = lam[m];
        double nv = nu_in[b * kNS + tid];
        if (!first) {
            zv += alpha * dz_g[m]; sv += alpha * ds_g[m]; lv += alpha * dl_g[m];
            z[m] = zv; s[m] = sv; lam[m] = lv;          // own slice: race-free
            nv += alpha * dnu_g[b * kNS + tid];
        }
        if (a == 0) {
            nu_out[b * kNS + tid] = nv;                 // parity buffer
            if (tid == 0) mu_g[b] = mu;                 // relay for dz
        }
        za[tid] = zv; sa[tid] = sv; la[tid] = lv;
        daf[tid] = (float)(lv / sv);
        nus[tid] = nv;
        labs[tid] = labels[b * kNS + tid];
    }
    // pad row slots (indices 100..103) of the panel arrays stay exact zero
    if (h == 0 && j2 >= kNS && j2 < kNSP) {
        #pragma unroll
        for (int bf = 0; bf < 2; ++bf)
            #pragma unroll
            for (int p = 0; p < kPan; ++p) { Wr[bf][p][j2] = 0.0f; Wsg[bf][p][j2] = 0.0f; }
    }
    __syncthreads();

    // Build both H columns in registers (fp32); fused fp64 partials of (K z_a).
    float h1[kRQ], h2[kRQ];
    double kz1 = 0.0, kz2 = 0.0;
    #pragma unroll
    for (int r = 0; r < kRQ; ++r) {
        const int i = base + r;
        if (i < kNS) {
            float kv1 = Kb[(size_t)i * kNS + j1];
            float kv2 = Kb[(size_t)i * kNS + js2];
            kz1 += (double)kv1 * za[i];
            kz2 += (double)kv2 * za[i];
            h1[r] = (i == j1)  ? (kv1 + 1.0f + daf[j1])  : kv1;
            h2[r] = (i == js2) ? (kv2 + 1.0f + daf[js2]) : kv2;
        } else { h1[r] = 0.0f; h2[r] = 0.0f; }
    }
    part[h][j1] = kz1;
    if (a2) part[h][j2] = kz2;
    if (h == 0) {   // seed panel 0 rows (0..3); sign vs k0=0 -> all +
        #pragma unroll
        for (int p = 0; p < kPan; ++p) {
            Wr [0][p][j1] = h1[p];  Wsg[0][p][j1] = h1[p];
            if (a2) { Wr[0][p][j2] = h2[p]; Wsg[0][p][j2] = h2[p]; }
        }
    }
    __syncthreads();
    if (tid < kNS) {
        const int i = tid;
        double kz = 0.0;
        #pragma unroll
        for (int g = 0; g < kGrp; ++g) kz += part[g][i];
        double yv = (labs[i] == a) ? 1.0 : 0.0;
        double rd = kz + za[i] - yv + la[i] + nus[i];
        double rp = za[i] + sa[i] - 0.1 * yv;      // h = C_REG*y
        double rc = la[i] * sa[i] - 0.1 * mu;      // sigma = 0.1
        r1s[i] = -rd + (rc - la[i] * rp) / sa[i];
    }

    // Panel-blocked Gauss-Jordan inverse: 25 panels, 1 barrier each.
    #pragma unroll 1
    for (int k0 = 0; k0 < kNS; k0 += kPan) {
        const int buf = (k0 >> 2) & 1, nbuf = 1 - buf;
        __syncthreads();                     // Wr/Wsg[buf] complete
        float B[4][4];
        #pragma unroll
        for (int p = 0; p < 4; ++p)
            #pragma unroll
            for (int q = 0; q < 4; ++q)
                B[p][q] = Wr[buf][p][k0 + q];

        const bool inp1 = (j1 >= k0) && (j1 < k0 + kPan);
        const bool inp2 = (js2 >= k0) && (js2 < k0 + kPan);
        float b1[4], b2[4];
        #pragma unroll
        for (int p = 0; p < 4; ++p) {
            b1[p] = inp1 ? ((j1  - k0 == p) ? 1.0f : 0.0f) : Wr[buf][p][j1];
            b2[p] = inp2 ? ((js2 - k0 == p) ? 1.0f : 0.0f) : Wr[buf][p][js2];
        }
        float m1[4], m2[4];
        adj4_solvef(B, b1, b2, m1, m2);
        const float scl1 = inp1 ? 0.0f : 1.0f;
        const float scl2 = inp2 ? 0.0f : 1.0f;
        PANEL_UPDATE2F(h1, h2, Wsg, buf, base, scl1, scl2, m1, m2);

        // panel rows get m directly (overwrite generic update)
        if (k0 < base + kRQ && k0 + kPan - 1 >= base) {
            #pragma unroll
            for (int r = 0; r < kRQ; ++r) {
                const int i = base + r;
                if (i >= k0 && i < k0 + kPan) {
                    const int p = i - k0;
                    h1[r] = m1[p];
                    h2[r] = m2[p];
                }
            }
        }
        // write-ahead next panel rows (raw + signed vs kn0)
        const int kn0 = k0 + kPan;
        if (kn0 < kNS && kn0 < base + kRQ && kn0 + kPan - 1 >= base) {
            #pragma unroll
            for (int r = 0; r < kRQ; ++r) {
                const int i = base + r;
                if (i >= kn0 && i < kn0 + kPan) {
                    const int p = i - kn0;
                    Wr [nbuf][p][j1] = h1[r];
                    Wsg[nbuf][p][j1] = (j1 < kn0) ? -h1[r] : h1[r];
                    if (a2) {
                        Wr [nbuf][p][j2] = h2[r];
                        Wsg[nbuf][p][j2] = (j2 < kn0) ? -h2[r] : h2[r];
                    }
                }
            }
        }
    }

    // Write Hinv (fp32, coalesced) + atomic S accumulation + t_a = Hinv*r1.
    float* Hb = Hinv + (size_t)(b * kNW + a) * kNS * kNS;
    float* Sb = Sg   + (size_t)b * kNS * kNS;
    double tp1 = 0.0, tp2 = 0.0;
    #pragma unroll
    for (int r = 0; r < kRQ; ++r) {
        const int i = base + r;
        if (i < kNS) {
            Hb[(size_t)i * kNS + j1] = h1[r];
            atomicAdd(&Sb[(size_t)i * kNS + j1], h1[r]);
            tp1 += (double)h1[r] * r1s[i];
            if (a2) {
                Hb[(size_t)i * kNS + j2] = h2[r];
                atomicAdd(&Sb[(size_t)i * kNS + j2], h2[r]);
                tp2 += (double)h2[r] * r1s[i];
            }
        }
    }
    part[h][j1] = tp1;
    if (a2) part[h][j2] = tp2;
    __syncthreads();
    if (tid < kNS) {
        double t = 0.0;
        #pragma unroll
        for (int g = 0; g < kGrp; ++g) t += part[g][tid];
        tvec[(size_t)(b * kNW + a) * kNS + tid] = t;
    }
}

// -------------------------------------------------------------------------
// One block (512 thr) per b: fp32 panel-blocked GJ solve S dnu = sum_a t_a + rp2.
// Loads the atomically pre-summed Sg (L2-resident). rhs is column 100.
__global__ __launch_bounds__(512) void schur_solve_kernel(
    const float* __restrict__ Sg, const double* __restrict__ tvec,
    const double* __restrict__ z, double* __restrict__ dnu_g)
{
    const int b = blockIdx.x;
    const int tid = threadIdx.x;
    const int h = tid >> 6;
    const int lane = tid & 63;
    const int base = h * kRQ;
    const int j1 = lane;
    const int j2 = 64 + lane;
    const bool a2 = (j2 <= kNS);       // lane <= 36; j2==100 is the rhs column
    const int js2 = a2 ? j2 : j1;

    __shared__ double rhs[kNS];
    __shared__ alignas(16) float Wr [2][kPan][kNSP + 8];
    __shared__ alignas(16) float Wsg[2][kPan][kNSP + 8];

    const float*  Sb = Sg   + (size_t)b * kNS * kNS;
    const double* tb = tvec + (size_t)b * kNW * kNS;
    const double* zb = z    + (size_t)b * kNZ;

    if (tid < kNS) {
        double acc = 0.0, rp2 = 0.0;
        #pragma unroll
        for (int a = 0; a < kNW; ++a) {
            acc += tb[a * kNS + tid];
            rp2 += zb[tid * kNW + a];
        }
        rhs[tid] = acc + rp2;
    }
    if (h == 0 && j2 > kNS && j2 < kNSP) {   // pad slots 101..103 -> zero
        #pragma unroll
        for (int bf = 0; bf < 2; ++bf)
            #pragma unroll
            for (int p = 0; p < kPan; ++p) { Wr[bf][p][j2] = 0.0f; Wsg[bf][p][j2] = 0.0f; }
    }
    __syncthreads();

    float h1[kRQ], h2[kRQ];
    #pragma unroll
    for (int r = 0; r < kRQ; ++r) {
        const int i = base + r;
        if (i < kNS) {
            h1[r] = Sb[(size_t)i * kNS + j1];
            h2[r] = (js2 == kNS) ? (float)rhs[i]
                  : Sb[(size_t)i * kNS + ((js2 < kNS) ? js2 : 0)];
        } else { h1[r] = 0.0f; h2[r] = 0.0f; }
    }
    if (h == 0) {
        #pragma unroll
        for (int p = 0; p < kPan; ++p) {
            Wr [0][p][j1] = h1[p];  Wsg[0][p][j1] = h1[p];
            if (a2) { Wr[0][p][j2] = h2[p]; Wsg[0][p][j2] = h2[p]; }
        }
    }

    #pragma unroll 1
    for (int k0 = 0; k0 < kNS; k0 += kPan) {
        const int buf = (k0 >> 2) & 1, nbuf = 1 - buf;
        __syncthreads();
        float B[4][4];
        #pragma unroll
        for (int p = 0; p < 4; ++p)
            #pragma unroll
            for (int q = 0; q < 4; ++q)
                B[p][q] = Wr[buf][p][k0 + q];

        const bool inp1 = (j1 >= k0) && (j1 < k0 + kPan);
        const bool inp2 = (js2 >= k0) && (js2 < k0 + kPan);   // never for j2==100
        float b1[4], b2[4];
        #pragma unroll
        for (int p = 0; p < 4; ++p) {
            b1[p] = inp1 ? ((j1  - k0 == p) ? 1.0f : 0.0f) : Wr[buf][p][j1];
            b2[p] = inp2 ? ((js2 - k0 == p) ? 1.0f : 0.0f) : Wr[buf][p][js2];
        }
        float m1[4], m2[4];
        adj4_solvef(B, b1, b2, m1, m2);
        const float scl1 = inp1 ? 0.0f : 1.0f;
        const float scl2 = inp2 ? 0.0f : 1.0f;
        PANEL_UPDATE2F(h1, h2, Wsg, buf, base, scl1, scl2, m1, m2);

        if (k0 < base + kRQ && k0 + kPan - 1 >= base) {
            #pragma unroll
            for (int r = 0; r < kRQ; ++r) {
                const int i = base + r;
                if (i >= k0 && i < k0 + kPan) {
                    const int p = i - k0;
                    h1[r] = m1[p];
                    h2[r] = m2[p];
                }
            }
        }
        const int kn0 = k0 + kPan;
        if (kn0 < kNS && kn0 < base + kRQ && kn0 + kPan - 1 >= base) {
            #pragma unroll
            for (int r = 0; r < kRQ; ++r) {
                const int i = base + r;
                if (i >= kn0 && i < kn0 + kPan) {
                    const int p = i - kn0;
                    Wr [nbuf][p][j1] = h1[r];
                    Wsg[nbuf][p][j1] = (j1 < kn0) ? -h1[r] : h1[r];
                    if (a2) {
                        Wr [nbuf][p][j2] = h2[r];
                        Wsg[nbuf][p][j2] = (j2 < kn0) ? -h2[r] : h2[r];
                    }
                }
            }
        }
    }

    if (j2 == kNS) {   // lane 36: rhs column now holds dnu for owned rows
        #pragma unroll
        for (int r = 0; r < kRQ; ++r) {
            const int i = base + r;
            if (i < kNS) dnu_g[(size_t)b * kNS + i] = (double)h2[r];
        }
    }
}

// -------------------------------------------------------------------------
// One block (512 thr) per (b,a): dz_a = t_a - Hinv_a*dnu, ds/dlam, per-block
// min step-ratio, 3 quadratic mu-partials, zero Sg for next iteration.
__global__ __launch_bounds__(512) void dz_kernel(
    const int* __restrict__ labels,
    const float* __restrict__ Hinv, const double* __restrict__ tvec,
    const double* __restrict__ dnu_g,
    const double* __restrict__ z, const double* __restrict__ s,
    const double* __restrict__ lam, const double* __restrict__ mu_g,
    double* __restrict__ dz_g, double* __restrict__ ds_g,
    double* __restrict__ dl_g, double* __restrict__ minr_g,
    double* __restrict__ part3_g, float* __restrict__ Sg)
{
    const int b = blockIdx.x / kNW;
    const int a = blockIdx.x - b * kNW;
    const int tid = threadIdx.x;
    const int h = tid >> 7;            // 0..3
    const int j = tid & 127;

    __shared__ double dnus[kNS];
    __shared__ double p4[4][kNS];
    __shared__ double red[512], rA[512], rB[512], rC[512];

    const float* Hb = Hinv + (size_t)(b * kNW + a) * kNS * kNS;

    if (tid < kNS) dnus[tid] = dnu_g[(size_t)b * kNS + tid];
    {
        float* Sb = Sg + (size_t)b * kNS * kNS + (size_t)a * (kNS * kNS / kNW);
        for (int e = tid; e < kNS * kNS / kNW; e += 512) Sb[e] = 0.0f;
    }
    __syncthreads();

    if (j < kNS) {
        double p = 0.0;
        #pragma unroll
        for (int r = 0; r < kNS / 4; ++r)
            p += (double)Hb[(size_t)(h * (kNS / 4) + r) * kNS + j] * dnus[h * (kNS / 4) + r];
        p4[h][j] = p;
    }
    __syncthreads();

    double lmin = 1e300, p0 = 0.0, p1 = 0.0, p2 = 0.0;
    if (tid < kNS) {
        const int i = tid;
        const size_t m = (size_t)b * kNZ + i * kNW + a;
        const double mu = mu_g[b];
        double dz = tvec[(size_t)(b * kNW + a) * kNS + i]
                  - (p4[0][i] + p4[1][i] + p4[2][i] + p4[3][i]);
        double yv = (labels[b * kNS + i] == a) ? 1.0 : 0.0;
        double zv = z[m], sv = s[m], lv = lam[m];
        double rp = zv + sv - 0.1 * yv;
        double rc = lv * sv - 0.1 * mu;
        double ds = -rp - dz;
        double dl = (-rc - lv * ds) / sv;
        dz_g[m] = dz; ds_g[m] = ds; dl_g[m] = dl;
        if (ds < 0.0) lmin = fmin(lmin, -sv / ds);
        if (dl < 0.0) lmin = fmin(lmin, -lv / dl);
        p0 = sv * lv;
        p1 = sv * dl + lv * ds;
        p2 = ds * dl;
    }
    red[tid] = lmin; rA[tid] = p0; rB[tid] = p1; rC[tid] = p2;
    __syncthreads();
    for (int off = 256; off > 0; off >>= 1) {
        if (tid < off) {
            red[tid] = fmin(red[tid], red[tid + off]);
            rA[tid] += rA[tid + off];
            rB[tid] += rB[tid + off];
            rC[tid] += rC[tid + off];
        }
        __syncthreads();
    }
    if (tid == 0) {
        minr_g[b * kNW + a] = red[0];
        double* pp = part3_g + (size_t)(b * kNW + a) * 3;
        pp[0] = rA[0]; pp[1] = rB[0]; pp[2] = rC[0];
    }
}

// -------------------------------------------------------------------------
// logits: 320 blocks (10 q-chunks of 15 per b). z_final applies the 15th
// (final) IPM step inline.
__global__ __launch_bounds__(256) void logits_kernel(const float* __restrict__ compat,
                                                     const double* __restrict__ z,
                                                     const double* __restrict__ dz_g,
                                                     const double* __restrict__ minr_g,
                                                     float* __restrict__ out)
{
    const int b = blockIdx.x / kNW;
    const int c = blockIdx.x - b * kNW;   // q-chunk 0..9
    const int tid = threadIdx.x;
    const float* cb = compat + (size_t)b * kNS * kNQ;
    const double* zb = z + (size_t)b * kNZ;
    __shared__ double zs[kNZ];
    double am = 1e300;
    #pragma unroll
    for (int aa = 0; aa < kNW; ++aa) am = fmin(am, minr_g[b * kNW + aa]);
    const double alpha = fmin(1.0, 0.99 * am);
    for (int m = tid; m < kNZ; m += 256)
        zs[m] = zb[m] + alpha * dz_g[(size_t)b * kNZ + m];
    __syncthreads();
    for (int idx = tid; idx < (kNQ / kNW) * kNW; idx += 256) {  // 150 items
        int ql = idx / kNW, n = idx - ql * kNW;
        int q = c * (kNQ / kNW) + ql;
        double acc = 0.0;
        for (int s2 = 0; s2 < kNS; ++s2)
            acc += (double)cb[(size_t)s2 * kNQ + q] * zs[s2 * kNW + n];
        out[(size_t)b * kNQ * kNW + q * kNW + n] = (float)acc;
    }
}

// -------------------------------------------------------------------------
extern "C" void kernel_launch(void* const* d_in, const int* in_sizes, int n_in,
                              void* d_out, int out_size, void* d_ws, size_t ws_size,
                              hipStream_t stream)
{
    const float* sup    = (const float*)d_in[0];   // (32,10,10,512)
    const int*   labels = (const int*)  d_in[1];   // (32,10,10)
    const float* qry    = (const float*)d_in[2];   // (32,10,15,512)
    float* out = (float*)d_out;                    // (32,150,10) fp32

    char* ws = (char*)d_ws;
    size_t off = 0;
    auto alloc = [&](size_t bytes) -> void* {
        void* p = ws + off;
        off += (bytes + 255) & ~(size_t)255;
        return p;
    };
    float*  Kf     = (float*) alloc(sizeof(float)  * kB * kNS * kNS);        // 1.28 MB
    double* z      = (double*)alloc(sizeof(double) * kB * kNZ);
    double* nuA    = (double*)alloc(sizeof(double) * kB * kNS);
    double* nuB    = (double*)alloc(sizeof(double) * kB * kNS);
    double* s      = (double*)alloc(sizeof(double) * kB * kNZ);
    double* lam    = (double*)alloc(sizeof(double) * kB * kNZ);
    double* mu_g   = (double*)alloc(sizeof(double) * kB);
    float*  Hinv   = (float*) alloc(sizeof(float)  * kB * kNW * kNS * kNS);  // 12.8 MB
    float*  Sg     = (float*) alloc(sizeof(float)  * kB * kNS * kNS);        // 1.28 MB
    double* tvec   = (double*)alloc(sizeof(double) * kB * kNW * kNS);
    double* dnu_g  = (double*)alloc(sizeof(double) * kB * kNS);
    double* dz_g   = (double*)alloc(sizeof(double) * kB * kNZ);
    double* ds_g   = (double*)alloc(sizeof(double) * kB * kNZ);
    double* dl_g   = (double*)alloc(sizeof(double) * kB * kNZ);
    double* minr_g = (double*)alloc(sizeof(double) * kB * kNW);
    double* part3_g= (double*)alloc(sizeof(double) * kB * kNW * 3);
    float*  compat = (float*) alloc(sizeof(float)  * kB * kNS * kNQ);        // 1.92 MB

    gemm_kernel<<<dim3(kNS / 2, kB), 256, 0, stream>>>(sup, qry, Kf, compat);
    init_kernel<<<kB, 256, 0, stream>>>(z, nuA, s, lam, mu_g, Sg);

    for (int it = 0; it < kIt; ++it) {
        const double* nu_in  = (it & 1) ? nuB : nuA;
        double*       nu_out = (it & 1) ? nuA : nuB;
        ipm_invert_kernel<<<kB * kNW, 512, 0, stream>>>(
            Kf, labels, z, s, lam, nu_in, nu_out,
            dnu_g, dz_g, ds_g, dl_g, minr_g, part3_g, mu_g,
            Hinv, Sg, tvec, (it == 0) ? 1 : 0);
        schur_solve_kernel<<<kB, 512, 0, stream>>>(Sg, tvec, z, dnu_g);
        dz_kernel<<<kB * kNW, 512, 0, stream>>>(labels, Hinv, tvec, dnu_g,
                                                z, s, lam, mu_g,
                                                dz_g, ds_g, dl_g, minr_g,
                                                part3_g, Sg);
    }

    logits_kernel<<<kB * kNW, 256, 0, stream>>>(compat, z, dz_g, minr_g, out);
}